// Round 7
// baseline (11804.634 us; speedup 1.0000x reference)
//
#include <hip/hip_runtime.h>

typedef unsigned short ushort_t;
typedef __attribute__((ext_vector_type(4))) float f32x4;
typedef __attribute__((ext_vector_type(8))) __bf16 bf16x8;

#define SEQ   512
#define BATCH 128
#define HID   1024
#define G4    4096
#define CHUNK 64
#define BH    (BATCH*HID)
#define NBLK  256
#define FLAG_STRIDE 32
#define SCAN_LDS (131072 + 32768)   // U 128KB + A-ring 4x8KB (sm aliases slot0)

__device__ __forceinline__ ushort_t f2bf(float f) {
  unsigned u = __float_as_uint(f);
  u += 0x7FFFu + ((u >> 16) & 1u);  // RNE
  return (ushort_t)(u >> 16);
}
__device__ __forceinline__ float bf2f(ushort_t h) {
  return __uint_as_float(((unsigned)h) << 16);
}
__device__ __forceinline__ float sigm(float x) { return 1.0f / (1.0f + __expf(-x)); }
__device__ __forceinline__ float ftanh(float x) {
  float xc = fminf(fmaxf(x, -15.f), 15.f);
  float t = __expf(2.f * xc);
  return (t - 1.f) / (t + 1.f);
}
__device__ __forceinline__ unsigned pkbf(float a, float b) {
  unsigned r;
  asm("v_cvt_pk_bf16_f32 %0, %1, %2" : "=v"(r) : "v"(a), "v"(b));
  return r;
}
__device__ __forceinline__ float lo16(unsigned u){ return __uint_as_float(u << 16); }
__device__ __forceinline__ float hi16(unsigned u){ return __uint_as_float(u & 0xffff0000u); }
__device__ __forceinline__ bf16x8 cvt8(float4 lo, float4 hi) {
  union { unsigned u[4]; bf16x8 v; } r;
  r.u[0] = pkbf(lo.x, lo.y); r.u[1] = pkbf(lo.z, lo.w);
  r.u[2] = pkbf(hi.x, hi.y); r.u[3] = pkbf(hi.z, hi.w);
  return r.v;
}

__device__ __forceinline__ void lds16(const ushort_t* g, ushort_t* l) {
  __builtin_amdgcn_global_load_lds(
      (const __attribute__((address_space(1))) unsigned int*)g,
      (__attribute__((address_space(3))) unsigned int*)l, 16, 0, 0);
}
// coherent (SC0|SC1): read at coherence point -> no acquire fence needed
__device__ __forceinline__ void lds16c(const ushort_t* g, ushort_t* l) {
  __builtin_amdgcn_global_load_lds(
      (const __attribute__((address_space(1))) unsigned int*)g,
      (__attribute__((address_space(3))) unsigned int*)l, 16, 0, 0x11);
}

// ---------------- preamble kernels ----------------
__global__ void cast_f32_bf16(const float* __restrict__ in, ushort_t* __restrict__ out, int n4) {
  int i = blockIdx.x * blockDim.x + threadIdx.x;
  if (i < n4) {
    float4 v = ((const float4*)in)[i];
    union { ushort_t u[4]; uint2 v2; } o;
    o.u[0] = f2bf(v.x); o.u[1] = f2bf(v.y); o.u[2] = f2bf(v.z); o.u[3] = f2bf(v.w);
    ((uint2*)out)[i] = o.v2;
  }
}

__global__ __launch_bounds__(256) void transpose_cast(const float* __restrict__ pw, ushort_t* __restrict__ pwt) {
  __shared__ float tile[32][33];
  int bx = blockIdx.x, by = blockIdx.y;
  int tx = threadIdx.x & 31, ty = threadIdx.x >> 5;
  for (int i = 0; i < 32; i += 8)
    tile[ty + i][tx] = pw[(size_t)(by*32 + ty + i)*2048 + bx*32 + tx];
  __syncthreads();
  for (int i = 0; i < 32; i += 8) {
    int r = ty + i;
    pwt[(size_t)(bx*32 + r)*4096 + by*32 + tx] = f2bf(tile[tx][r]);
  }
}

__global__ void bias_fold(const float* __restrict__ qW, const float* __restrict__ pb, float* __restrict__ b2) {
  int r = blockIdx.x;
  int j = r & (HID-1), gb = r & ~(HID-1);
  float s = 0.f;
  for (int k = threadIdx.x; k < HID; k += 64)
    s += qW[(size_t)j*HID + k] * pb[gb + k];
  for (int off = 32; off; off >>= 1) s += __shfl_down(s, off, 64);
  if (threadIdx.x == 0) b2[r] = s;
}

// 128x128 bf16 GEMM (m97 structure) — weight fold: W2 = blockdiag(qW) @ proj_W
__global__ __launch_bounds__(256) void gemm128(
    const ushort_t* __restrict__ A, int lda, unsigned arow_mask,
    const ushort_t* __restrict__ B, int ldb, unsigned bko_mask,
    const float* __restrict__ bias, ushort_t* __restrict__ C, int ldc, int K)
{
  __shared__ __align__(16) ushort_t Al[128*64];
  __shared__ __align__(16) ushort_t Bl[128*64];
  const int tid = threadIdx.x, wv = tid >> 6, ln = tid & 63;
  const int bn = blockIdx.x, bm = blockIdx.y;
  const int bko = (int)(((unsigned)(bm << 7)) & bko_mask);
  const int m0 = (wv & 1) << 6, n0 = (wv >> 1) << 6;
  f32x4 acc[4][4] = {};
  for (int k0 = 0; k0 < K; k0 += 64) {
    for (int rr = 0; rr < 4; ++rr) {
      int r0 = (rr << 5) + (wv << 3);
      unsigned ga = ((unsigned)((bm << 7) + r0 + (ln >> 3))) & arow_mask;
      lds16(A + (size_t)ga*lda + k0 + ((ln & 7) << 3), &Al[r0 << 6]);
      unsigned gbr = (unsigned)((bn << 7) + r0 + (ln >> 3));
      lds16(B + (size_t)gbr*ldb + bko + k0 + ((ln & 7) << 3), &Bl[r0 << 6]);
    }
    __syncthreads();
    for (int kk = 0; kk < 64; kk += 32) {
      const int lrow = ln & 15, lk = kk + ((ln >> 4) << 3);
      bf16x8 af[4], bfr[4];
      for (int i = 0; i < 4; ++i) af[i]  = *(const bf16x8*)&Al[((m0 + (i << 4) + lrow) << 6) + lk];
      for (int j = 0; j < 4; ++j) bfr[j] = *(const bf16x8*)&Bl[((n0 + (j << 4) + lrow) << 6) + lk];
      for (int i = 0; i < 4; ++i)
        for (int j = 0; j < 4; ++j)
          acc[i][j] = __builtin_amdgcn_mfma_f32_16x16x32_bf16(af[i], bfr[j], acc[i][j], 0, 0, 0);
    }
    __syncthreads();
  }
  for (int i = 0; i < 4; ++i)
    for (int j = 0; j < 4; ++j) {
      int col = (bn << 7) + n0 + (j << 4) + (ln & 15);
      float bv = bias ? bias[col] : 0.f;
      for (int r = 0; r < 4; ++r) {
        int row = (bm << 7) + m0 + (i << 4) + ((ln >> 4) << 2) + r;
        C[(size_t)row*ldc + col] = f2bf(acc[i][j][r] + bv);
      }
    }
}

// ---------------- single-launch persistent scan + fused P-GEMM ----------------
// 256 blocks (1/CU), all 512 steps. block: rblk=bid&3 (32 hx rows),
// cblk=bid>>2 (16 cols x 4 gates, wv=gate). 4 independent sync groups.
// During each step's poll window, each thread computes its OWN P slice for the
// same step-slot of the NEXT chunk (thread-private round trip, no coherence).
__global__ __launch_bounds__(256, 1) void qlstm_scan(
    unsigned* __restrict__ Pp,           // [256 blk][64 tl][4 wv][64 ln][4] uints
    const ushort_t* __restrict__ W2,     // [4096][2048] bf16; V=cols[0,1024) U=[1024,2048)
    const float* __restrict__ x,         // (512,128,1024) f32
    const float* __restrict__ b2,        // [4096] f32
    ushort_t* __restrict__ hxb,          // 3 rotating [128][1024] bf16
    float* __restrict__ out,             // outs/hx/cx concatenated
    unsigned* __restrict__ flags)        // [4 groups][64 blocks], 128B stride
{
  extern __shared__ __align__(16) ushort_t lds[];
  ushort_t* Ul = lds;                    // [8 ck][64 rows][128] swizzled, 128 KB
  ushort_t* Ar = lds + 65536;            // 4 slots x [32][128], 32 KB
  float*    sm = (float*)(lds + 65536);  // aliases Ar slot0 (epilogue only)

  const int tid = threadIdx.x, wv = tid >> 6, ln = tid & 63;
  const int rblk = blockIdx.x & 3, cblk = blockIdx.x >> 2;
  const int lr = ln & 15, lg = ln >> 4;
  unsigned* gflags = flags + (size_t)rblk*64*FLAG_STRIDE;

  // ---- stage resident U once, chunk-major, XOR-swizzled src
  for (int ck = 0; ck < 8; ++ck)
    for (int rr = 0; rr < 4; ++rr) {
      int lrr = rr*16 + wv*4 + (ln >> 4);
      int grow = ((lrr >> 4) << 10) + cblk*16 + (lrr & 15);
      int gcol = ck*128 + (((ln & 15) ^ (lrr & 7)) << 3);
      lds16(W2 + (size_t)grow*2048 + 1024 + gcol, &Ul[ck*8192 + (rr*16 + wv*4)*128]);
    }

  // ---- epilogue slice: row b_loc, adjacent cols j0,j0+1
  const int b_loc = tid >> 3;
  const int j0    = (tid & 7) << 1;
  const size_t ci = (size_t)(rblk*32 + b_loc)*1024 + cblk*16 + j0;
  float2 cxr; cxr.x = 0.f; cxr.y = 0.f;

  // ---- fused P-GEMM slab: thread-private P slice, 2 tiles x K=1024
  const float bv = b2[(wv << 10) + cblk*16 + lr];
  const ushort_t* vrow = W2 + (size_t)((wv << 10) + cblk*16 + lr)*2048;
  unsigned* pslot = Pp + ((((size_t)blockIdx.x*CHUNK)*4 + wv)*64 + lg*16 + lr)*4;

  auto slab = [&](int cn, int tl) {
    const float* xa = x + ((size_t)(cn*CHUNK + tl)*BATCH + rblk*32 + lr)*HID;
    const float* xb = xa + 16*HID;
    f32x4 p0 = {}, p1 = {};
    #pragma unroll 2
    for (int ks = 0; ks < 32; ++ks) {
      int k = ks*32 + lg*8;
      float4 a0l = *(const float4*)(xa + k);
      float4 a0h = *(const float4*)(xa + k + 4);
      float4 a1l = *(const float4*)(xb + k);
      float4 a1h = *(const float4*)(xb + k + 4);
      union { uint4 u; bf16x8 v; } bb; bb.u = *(const uint4*)(vrow + k);
      bf16x8 a0 = cvt8(a0l, a0h), a1 = cvt8(a1l, a1h);
      p0 = __builtin_amdgcn_mfma_f32_16x16x32_bf16(a0, bb.v, p0, 0, 0, 0);
      p1 = __builtin_amdgcn_mfma_f32_16x16x32_bf16(a1, bb.v, p1, 0, 0, 0);
    }
    uint4 pk;
    pk.x = pkbf(p0[0] + bv, p0[1] + bv);
    pk.y = pkbf(p0[2] + bv, p0[3] + bv);
    pk.z = pkbf(p1[0] + bv, p1[1] + bv);
    pk.w = pkbf(p1[2] + bv, p1[3] + bv);
    *(uint4*)(pslot + (size_t)tl*1024) = pk;
  };
  auto load_pv = [&](int tl, float* pv) {
    uint4 u = *(const uint4*)(pslot + (size_t)tl*1024);
    pv[0] = lo16(u.x); pv[1] = hi16(u.x);
    pv[2] = lo16(u.y); pv[3] = hi16(u.y);
    pv[4] = lo16(u.z); pv[5] = hi16(u.z);
    pv[6] = lo16(u.w); pv[7] = hi16(u.w);
  };

  auto stageA = [&](int slot, int k0, const ushort_t* hxR) {
    #pragma unroll
    for (int rr = 0; rr < 2; ++rr) {
      int row = rr*16 + wv*4 + (ln >> 4);
      int gcol = ((ln & 15) ^ (row & 7)) << 3;
      lds16c(hxR + (size_t)(rblk*32 + row)*1024 + k0 + gcol,
             &Ar[slot*4096 + (rr*16 + wv*4)*128]);
    }
  };

  // ---- preloop: compute chunk 0's P (replaces standalone gemm256 + casts)
  for (int tl = 0; tl < CHUNK; ++tl) slab(0, tl);
  asm volatile("s_waitcnt vmcnt(0)" ::: "memory");

  float pv[8];
  load_pv(0, pv);

  for (int t = 0; t < SEQ; ++t) {
    const int tl = t & (CHUNK - 1);
    const ushort_t* hxR = hxb + (size_t)(t % 3)*BH;
    ushort_t*       hxW = hxb + (size_t)((t + 1) % 3)*BH;

    f32x4 acc0 = {}, acc1 = {};
    stageA(0, 0, hxR);
    stageA(1, 128, hxR);
    stageA(2, 256, hxR);

    #define COMPUTE_CK(CK)                                                         \
      {                                                                            \
        const int aslot = (CK) & 3;                                                \
        _Pragma("unroll")                                                          \
        for (int k4 = 0; k4 < 4; ++k4) {                                           \
          int s = k4*4 + (ln >> 4);                                                \
          int ar0 = ln & 15, ar1 = 16 + (ln & 15);                                 \
          int brow = wv*16 + (ln & 15);                                            \
          bf16x8 a0 = *(const bf16x8*)&Ar[aslot*4096 + ar0*128 + ((s ^ (ar0 & 7)) << 3)]; \
          bf16x8 a1 = *(const bf16x8*)&Ar[aslot*4096 + ar1*128 + ((s ^ (ar1 & 7)) << 3)]; \
          bf16x8 bb = *(const bf16x8*)&Ul[(CK)*8192 + brow*128 + ((s ^ (brow & 7)) << 3)]; \
          acc0 = __builtin_amdgcn_mfma_f32_16x16x32_bf16(a0, bb, acc0, 0, 0, 0);   \
          acc1 = __builtin_amdgcn_mfma_f32_16x16x32_bf16(a1, bb, acc1, 0, 0, 0);   \
        }                                                                          \
      }
    #define STEP_CK(CK, WN, DOSTAGE)                                               \
      asm volatile("s_waitcnt vmcnt(" #WN ")" ::: "memory");                       \
      __builtin_amdgcn_s_barrier();                                                \
      if (DOSTAGE) stageA(((CK)+3) & 3, ((CK)+3)*128, hxR);                        \
      COMPUTE_CK(CK)

    STEP_CK(0, 4, 1) STEP_CK(1, 4, 1) STEP_CK(2, 4, 1)
    STEP_CK(3, 4, 1) STEP_CK(4, 4, 1)
    STEP_CK(5, 4, 0) STEP_CK(6, 2, 0) STEP_CK(7, 0, 0)
    #undef STEP_CK
    #undef COMPUTE_CK

    // ---- epilogue: inner sigmoid -> cross-gate exchange via sm
    #pragma unroll
    for (int i = 0; i < 2; ++i)
      #pragma unroll
      for (int r = 0; r < 4; ++r) {
        int bl = i*16 + ((ln >> 4) << 2) + r;
        float v = (i ? acc1[r] : acc0[r]) + pv[i*4+r];
        sm[wv*512 + bl*16 + (ln & 15)] = sigm(v);
      }
    __syncthreads();
    float2 h2;
    {
      const float2* sm2 = (const float2*)sm;
      int e = b_loc*8 + (j0 >> 1);
      float2 sF = sm2[0*256 + e], sI = sm2[1*256 + e];
      float2 sG = sm2[2*256 + e], sO = sm2[3*256 + e];
      float f0 = sigm(sF.x), i0 = sigm(sI.x), g0 = ftanh(sG.x), o0 = sigm(sO.x);
      float f1 = sigm(sF.y), i1 = sigm(sI.y), g1 = ftanh(sG.y), o1 = sigm(sO.y);
      float cn0 = f0*cxr.x + i0*g0, cn1 = f1*cxr.y + i1*g1;
      float h0 = o0*ftanh(cn0),     h1 = o1*ftanh(cn1);
      cxr.x = cn0; cxr.y = cn1;
      h2.x = h0; h2.y = h1;
      unsigned hp = (unsigned)f2bf(h0) | ((unsigned)f2bf(h1) << 16);
      __hip_atomic_store((unsigned*)&hxW[ci], hp,
                         __ATOMIC_RELAXED, __HIP_MEMORY_SCOPE_AGENT);
    }

    if (t != SEQ - 1) {
      const unsigned gen = (unsigned)(t + 1);
      // arrive: drain hx stores, block-sync, publish own flag line
      asm volatile("s_waitcnt vmcnt(0)" ::: "memory");
      __syncthreads();
      if (tid == 0)
        __hip_atomic_store(gflags + (size_t)cblk*FLAG_STRIDE, gen,
                           __ATOMIC_RELAXED, __HIP_MEMORY_SCOPE_AGENT);
      // off-critical-path work while flags converge:
      *(float2*)&out[(size_t)t*BH + ci] = h2;
      float pvn[8];
      load_pv((t + 1) & (CHUNK - 1), pvn);
      if (t < SEQ - CHUNK) slab((t >> 6) + 1, tl);   // next chunk's P, same slot
      if (tid < 64) {
        int it = 0;
        for (;;) {
          unsigned a = __hip_atomic_load(gflags + (size_t)tid*FLAG_STRIDE,
                                         __ATOMIC_RELAXED, __HIP_MEMORY_SCOPE_AGENT);
          if (__all(a >= gen)) break;
          if ((++it & 255) == 0) __builtin_amdgcn_fence(__ATOMIC_ACQUIRE, "agent");
          __builtin_amdgcn_s_sleep(1);
        }
      }
      __syncthreads();
      asm volatile("s_waitcnt vmcnt(0)" ::: "memory");  // drain slab/out stores
      #pragma unroll
      for (int q = 0; q < 8; ++q) pv[q] = pvn[q];
    } else {
      *(float2*)&out[(size_t)t*BH + ci] = h2;
      *(float2*)&out[(size_t)SEQ*BH + ci] = h2;          // final hx
    }
  }
  *(float2*)&out[(size_t)(SEQ + 1)*BH + ci] = cxr;       // final cx
}

extern "C" void kernel_launch(void* const* d_in, const int* in_sizes, int n_in,
                              void* d_out, int out_size, void* d_ws, size_t ws_size,
                              hipStream_t stream) {
  const float* x  = (const float*)d_in[0];   // (512,128,1024)
  const float* pW = (const float*)d_in[1];   // (4096,2048)
  const float* pb = (const float*)d_in[2];   // (4096)
  const float* qW = (const float*)d_in[3];   // (1024,1024)
  float* out = (float*)d_out;

  char* w = (char*)d_ws;
  auto carve = [&](size_t bytes) { char* p = w; w += (bytes + 255) & ~(size_t)255; return p; };
  ushort_t* qWbf = (ushort_t*)carve((size_t)HID*HID*2);          //  2 MB
  ushort_t* pWt  = (ushort_t*)carve((size_t)2048*4096*2);        // 16 MB
  ushort_t* W2   = (ushort_t*)carve((size_t)4096*2048*2);        // 16 MB
  float*    b2   = (float*)   carve((size_t)4096*4);
  ushort_t* hxb  = (ushort_t*)carve((size_t)3*BH*2);             // 1.5 MB
  unsigned* flags= (unsigned*)carve((size_t)NBLK*FLAG_STRIDE*4); // 32 KB
  unsigned* Pp   = (unsigned*)carve((size_t)NBLK*CHUNK*1024*4);  // 64 MB

  (void)hipFuncSetAttribute((const void*)qlstm_scan,
                            hipFuncAttributeMaxDynamicSharedMemorySize, SCAN_LDS);

  // weight folding: W2 = blockdiag(qW) @ proj_W  (bf16), b2 = qW @ b_g
  cast_f32_bf16<<<(HID*HID/4 + 255)/256, 256, 0, stream>>>(qW, qWbf, HID*HID/4);
  transpose_cast<<<dim3(64, 128), 256, 0, stream>>>(pW, pWt);
  bias_fold<<<4096, 64, 0, stream>>>(qW, pb, b2);
  gemm128<<<dim3(16, 32), 256, 0, stream>>>(qWbf, 1024, 1023u, pWt, 4096, ~1023u, nullptr, W2, 2048, 1024);

  hipMemsetAsync(hxb, 0, (size_t)BH*2, stream);        // h_{-1} = 0
  hipMemsetAsync(flags, 0, (size_t)NBLK*FLAG_STRIDE*4, stream);

  unsigned* Ppa = Pp; const ushort_t* W2a = W2; const float* xa = x;
  const float* b2a = b2; ushort_t* hxa = hxb; float* outa = out; unsigned* fla = flags;
  void* args[7] = { &Ppa, &W2a, &xa, &b2a, &hxa, &outa, &fla };
  hipLaunchCooperativeKernel((const void*)qlstm_scan, dim3(NBLK), dim3(256),
                             args, SCAN_LDS, stream);
}

// Round 8
// 4407.944 us; speedup vs baseline: 2.6780x; 2.6780x over previous
//
#include <hip/hip_runtime.h>

typedef unsigned short ushort_t;
typedef __attribute__((ext_vector_type(4))) float f32x4;
typedef __attribute__((ext_vector_type(8))) __bf16 bf16x8;

#define SEQ   512
#define BATCH 128
#define HID   1024
#define G4    4096
#define CHUNK 64
#define BH    (BATCH*HID)
#define NBLK  256
#define FLAG_STRIDE 32
#define SCAN_LDS 131072            // Ul 64KB + 2 A-rings 2x32KB (sm aliases ring slot0)
#define GEMM256_LDS 131072

__device__ __forceinline__ ushort_t f2bf(float f) {
  unsigned u = __float_as_uint(f);
  u += 0x7FFFu + ((u >> 16) & 1u);  // RNE
  return (ushort_t)(u >> 16);
}
__device__ __forceinline__ float bf2f(ushort_t h) {
  return __uint_as_float(((unsigned)h) << 16);
}
__device__ __forceinline__ float sigm(float x) { return 1.0f / (1.0f + __expf(-x)); }
__device__ __forceinline__ float ftanh(float x) {
  float xc = fminf(fmaxf(x, -15.f), 15.f);
  float t = __expf(2.f * xc);
  return (t - 1.f) / (t + 1.f);
}

__device__ __forceinline__ void lds16(const ushort_t* g, ushort_t* l) {
  __builtin_amdgcn_global_load_lds(
      (const __attribute__((address_space(1))) unsigned int*)g,
      (__attribute__((address_space(3))) unsigned int*)l, 16, 0, 0);
}
// coherent (SC0|SC1): read at coherence point -> no acquire fence needed
__device__ __forceinline__ void lds16c(const ushort_t* g, ushort_t* l) {
  __builtin_amdgcn_global_load_lds(
      (const __attribute__((address_space(1))) unsigned int*)g,
      (__attribute__((address_space(3))) unsigned int*)l, 16, 0, 0x11);
}

// ---------------- preamble kernels ----------------
__global__ void cast_f32_bf16(const float* __restrict__ in, ushort_t* __restrict__ out, int n4) {
  int i = blockIdx.x * blockDim.x + threadIdx.x;
  if (i < n4) {
    float4 v = ((const float4*)in)[i];
    union { ushort_t u[4]; uint2 v2; } o;
    o.u[0] = f2bf(v.x); o.u[1] = f2bf(v.y); o.u[2] = f2bf(v.z); o.u[3] = f2bf(v.w);
    ((uint2*)out)[i] = o.v2;
  }
}

__global__ __launch_bounds__(256) void transpose_cast(const float* __restrict__ pw, ushort_t* __restrict__ pwt) {
  __shared__ float tile[32][33];
  int bx = blockIdx.x, by = blockIdx.y;
  int tx = threadIdx.x & 31, ty = threadIdx.x >> 5;
  for (int i = 0; i < 32; i += 8)
    tile[ty + i][tx] = pw[(size_t)(by*32 + ty + i)*2048 + bx*32 + tx];
  __syncthreads();
  for (int i = 0; i < 32; i += 8) {
    int r = ty + i;
    pwt[(size_t)(bx*32 + r)*4096 + by*32 + tx] = f2bf(tile[tx][r]);
  }
}

__global__ void bias_fold(const float* __restrict__ qW, const float* __restrict__ pb, float* __restrict__ b2) {
  int r = blockIdx.x;
  int j = r & (HID-1), gb = r & ~(HID-1);
  float s = 0.f;
  for (int k = threadIdx.x; k < HID; k += 64)
    s += qW[(size_t)j*HID + k] * pb[gb + k];
  for (int off = 32; off; off >>= 1) s += __shfl_down(s, off, 64);
  if (threadIdx.x == 0) b2[r] = s;
}

// 128x128 bf16 GEMM (m97 structure) — weight fold: W2 = blockdiag(qW) @ proj_W
__global__ __launch_bounds__(256) void gemm128(
    const ushort_t* __restrict__ A, int lda, unsigned arow_mask,
    const ushort_t* __restrict__ B, int ldb, unsigned bko_mask,
    const float* __restrict__ bias, ushort_t* __restrict__ C, int ldc, int K)
{
  __shared__ __align__(16) ushort_t Al[128*64];
  __shared__ __align__(16) ushort_t Bl[128*64];
  const int tid = threadIdx.x, wv = tid >> 6, ln = tid & 63;
  const int bn = blockIdx.x, bm = blockIdx.y;
  const int bko = (int)(((unsigned)(bm << 7)) & bko_mask);
  const int m0 = (wv & 1) << 6, n0 = (wv >> 1) << 6;
  f32x4 acc[4][4] = {};
  for (int k0 = 0; k0 < K; k0 += 64) {
    for (int rr = 0; rr < 4; ++rr) {
      int r0 = (rr << 5) + (wv << 3);
      unsigned ga = ((unsigned)((bm << 7) + r0 + (ln >> 3))) & arow_mask;
      lds16(A + (size_t)ga*lda + k0 + ((ln & 7) << 3), &Al[r0 << 6]);
      unsigned gbr = (unsigned)((bn << 7) + r0 + (ln >> 3));
      lds16(B + (size_t)gbr*ldb + bko + k0 + ((ln & 7) << 3), &Bl[r0 << 6]);
    }
    __syncthreads();
    for (int kk = 0; kk < 64; kk += 32) {
      const int lrow = ln & 15, lk = kk + ((ln >> 4) << 3);
      bf16x8 af[4], bfr[4];
      for (int i = 0; i < 4; ++i) af[i]  = *(const bf16x8*)&Al[((m0 + (i << 4) + lrow) << 6) + lk];
      for (int j = 0; j < 4; ++j) bfr[j] = *(const bf16x8*)&Bl[((n0 + (j << 4) + lrow) << 6) + lk];
      for (int i = 0; i < 4; ++i)
        for (int j = 0; j < 4; ++j)
          acc[i][j] = __builtin_amdgcn_mfma_f32_16x16x32_bf16(af[i], bfr[j], acc[i][j], 0, 0, 0);
    }
    __syncthreads();
  }
  for (int i = 0; i < 4; ++i)
    for (int j = 0; j < 4; ++j) {
      int col = (bn << 7) + n0 + (j << 4) + (ln & 15);
      float bv = bias ? bias[col] : 0.f;
      for (int r = 0; r < 4; ++r) {
        int row = (bm << 7) + m0 + (i << 4) + ((ln >> 4) << 2) + r;
        C[(size_t)row*ldc + col] = f2bf(acc[i][j][r] + bv);
      }
    }
}

// ---------------- 256x256 8-phase bf16 GEMM: P = x @ V^T + b2 (r6, verified) ----
__global__ __launch_bounds__(512) void gemm256(
    const ushort_t* __restrict__ A, const ushort_t* __restrict__ B,
    const float* __restrict__ bias, ushort_t* __restrict__ C)
{
  extern __shared__ __align__(16) ushort_t lds[];
  ushort_t* LA = lds;
  ushort_t* LB = lds + 32768;
  const int tid = threadIdx.x, wv8 = tid >> 6, ln = tid & 63;
  const int wm = wv8 >> 2, wn = wv8 & 3;
  const int bn = blockIdx.x, bm = blockIdx.y;
  const int lr = ln & 15, lg = ln >> 4;

  f32x4 acc[8][4] = {};
  bf16x8 af[4][2], bfr[4][2];

  auto stA = [&](int db, int half, int kt) {
    ushort_t* d = LA + db*16384 + half*8192 + (wv8 << 9);
    const int ce = ((ln & 7) ^ (ln >> 3)) << 3;
    #pragma unroll
    for (int p = 0; p < 2; ++p) {
      int rr = half*128 + p*64 + (wv8 << 3) + (ln >> 3);
      lds16(A + (size_t)(bm*256 + rr)*1024 + kt*64 + ce, d + p*4096);
    }
  };
  auto stB = [&](int db, int half, int kt) {
    ushort_t* d = LB + db*16384 + half*8192 + (wv8 << 9);
    const int ce = ((ln & 7) ^ (ln >> 3)) << 3;
    #pragma unroll
    for (int p = 0; p < 2; ++p) {
      int rr = half*128 + p*64 + (wv8 << 3) + (ln >> 3);
      lds16(B + (size_t)(bn*256 + rr)*2048 + kt*64 + ce, d + p*4096);
    }
  };

#define RD_A(DB, MQ) { _Pragma("unroll") for (int i_ = 0; i_ < 4; ++i_) { \
    const int row_ = ((MQ)*4 + i_)*16 + lr; \
    const ushort_t* b_ = &LA[(DB)*16384 + wm*8192 + row_*64]; \
    af[i_][0] = *(const bf16x8*)&b_[ (lg << 3)       ^ ((lr & 7) << 3)]; \
    af[i_][1] = *(const bf16x8*)&b_[((lg << 3) | 32) ^ ((lr & 7) << 3)]; } }

#define RD_B(DB, NQ) { _Pragma("unroll") for (int j_ = 0; j_ < 2; ++j_) { \
    const int row_ = (wn & 1)*64 + ((NQ)*2 + j_)*16 + lr; \
    const ushort_t* b_ = &LB[(DB)*16384 + (wn >> 1)*8192 + row_*64]; \
    bfr[(NQ)*2 + j_][0] = *(const bf16x8*)&b_[ (lg << 3)       ^ ((lr & 7) << 3)]; \
    bfr[(NQ)*2 + j_][1] = *(const bf16x8*)&b_[((lg << 3) | 32) ^ ((lr & 7) << 3)]; } }

#define QUAD(MQ, NQ) \
  __builtin_amdgcn_s_setprio(1); \
  { _Pragma("unroll") for (int i_ = 0; i_ < 4; ++i_) \
      _Pragma("unroll") for (int j_ = 0; j_ < 2; ++j_) \
        _Pragma("unroll") for (int k_ = 0; k_ < 2; ++k_) \
          acc[(MQ)*4 + i_][(NQ)*2 + j_] = __builtin_amdgcn_mfma_f32_16x16x32_bf16( \
              af[i_][k_], bfr[(NQ)*2 + j_][k_], acc[(MQ)*4 + i_][(NQ)*2 + j_], 0, 0, 0); } \
  __builtin_amdgcn_s_setprio(0);

#define BAR() __builtin_amdgcn_s_barrier()
#define LGK0() do { asm volatile("s_waitcnt lgkmcnt(0)" ::: "memory"); \
                    __builtin_amdgcn_sched_barrier(0); } while (0)
#define VM4() do { asm volatile("s_waitcnt vmcnt(4)" ::: "memory"); \
                   __builtin_amdgcn_sched_barrier(0); } while (0)

  stA(0,0,0); stA(0,1,0); stB(0,0,0); stB(0,1,0); stB(1,0,1); stB(1,1,1);
  asm volatile("s_waitcnt vmcnt(4)" ::: "memory");
  BAR();

  for (int i = 0; i < 8; ++i) {
    const int k1 = 2*i + 1, k2 = 2*i + 2, k3 = 2*i + 3;
    RD_A(0,0); RD_B(0,0); stA(1,0,k1);            BAR(); LGK0(); QUAD(0,0); BAR();
    RD_B(0,1); stA(1,1,k1);                       BAR(); LGK0(); QUAD(0,1); BAR();
    RD_A(0,1); if (k2 < 16) stB(0,0,k2);          BAR(); LGK0(); QUAD(1,0); BAR();
    if (k2 < 16) stB(0,1,k2);                     BAR();         QUAD(1,1); VM4(); BAR();
    RD_A(1,0); RD_B(1,0); if (k2 < 16) stA(0,0,k2); BAR(); LGK0(); QUAD(0,0); BAR();
    RD_B(1,1); if (k2 < 16) stA(0,1,k2);          BAR(); LGK0(); QUAD(0,1); BAR();
    RD_A(1,1); if (k3 < 16) stB(1,0,k3);          BAR(); LGK0(); QUAD(1,0); BAR();
    if (k3 < 16) stB(1,1,k3);                     BAR();         QUAD(1,1); VM4(); BAR();
  }

  const int crow0 = bm*256 + wm*128;
  const int ccol0 = bn*256 + wn*64;
  #pragma unroll
  for (int m = 0; m < 8; ++m)
    #pragma unroll
    for (int n = 0; n < 4; ++n) {
      int col = ccol0 + n*16 + lr;
      float bv = bias[col];
      #pragma unroll
      for (int r = 0; r < 4; ++r) {
        int row = crow0 + m*16 + lg*4 + r;
        C[(size_t)row*4096 + col] = f2bf(acc[m][n][r] + bv);
      }
    }
#undef RD_A
#undef RD_B
#undef QUAD
#undef BAR
#undef LGK0
#undef VM4
}

// ---------------- dual-stream persistent scan ----------------
// 256 blocks: pr = bid&1 -> rblk pair {2pr, 2pr+1}; cblk8 = bid>>1 in [0,128)
// (8 hidden cols x 4 gates per stream). Per tick: stream A step t, then stream B
// step t — each stream's flag-visibility latency hides under the other's compute.
__device__ __forceinline__ void stream_step(
    ushort_t* __restrict__ Ar, float* __restrict__ sm,
    const ushort_t* __restrict__ Ul,
    const ushort_t* __restrict__ hxR, ushort_t* __restrict__ hxW,
    int rbase, unsigned* __restrict__ fl,
    const ushort_t* __restrict__ Pt,   // P + (tl*128 + rbase)*4096
    int pcol, float2& cx, size_t ci, float* __restrict__ outt,
    unsigned t, int wv, int ln, int tid, int cblk8)
{
  const int rh = wv & 1, uh = wv >> 1;
  const int lr15 = ln & 15, lg = ln >> 4;

  // poll: 128 flags of this rblk group (2 per lane); hx(t) ready when all >= t
  for (;;) {
    unsigned a = __hip_atomic_load(fl + (size_t)ln*FLAG_STRIDE,
                                   __ATOMIC_RELAXED, __HIP_MEMORY_SCOPE_AGENT);
    unsigned b = __hip_atomic_load(fl + (size_t)(64 + ln)*FLAG_STRIDE,
                                   __ATOMIC_RELAXED, __HIP_MEMORY_SCOPE_AGENT);
    if (__all(a >= t && b >= t)) break;
    __builtin_amdgcn_s_sleep(1);
  }

  auto stg = [&](int slot, int k0) {
    #pragma unroll
    for (int rr = 0; rr < 2; ++rr) {
      int row = rr*16 + wv*4 + (ln >> 4);
      int gcol = ((ln & 15) ^ (row & 7)) << 3;
      lds16c(hxR + (size_t)(rbase + row)*1024 + k0 + gcol,
             &Ar[slot*4096 + (rr*16 + wv*4)*128]);
    }
  };
  f32x4 acc = {};
  stg(0, 0); stg(1, 128); stg(2, 256);
  const int ar = rh*16 + lr15, ur = uh*16 + lr15;
  ushort_t pv0, pv1, pv2, pv3;

#define CCK(CK) { _Pragma("unroll") for (int k4 = 0; k4 < 4; ++k4) { \
    int s = k4*4 + lg; \
    bf16x8 av = *(const bf16x8*)&Ar[((CK)&3)*4096 + ar*128 + ((s ^ (ar & 7)) << 3)]; \
    bf16x8 bv = *(const bf16x8*)&Ul[(CK)*4096 + ur*128 + ((s ^ (ur & 7)) << 3)]; \
    acc = __builtin_amdgcn_mfma_f32_16x16x32_bf16(av, bv, acc, 0, 0, 0); } }
#define SCK(CK, WN, DS) \
  asm volatile("s_waitcnt vmcnt(" #WN ")" ::: "memory"); \
  __builtin_amdgcn_s_barrier(); \
  if (DS) stg(((CK)+3)&3, ((CK)+3)*128); \
  CCK(CK)

  SCK(0,4,1) SCK(1,4,1) SCK(2,4,1) SCK(3,4,1) SCK(4,4,1)
  SCK(5,4,0)
  // issue pv loads here (after all ring stages): newest in the vmem queue,
  // so SCK(6)=vmcnt(10), SCK(7)=vmcnt(8) still complete slots 6,7 exactly.
  {
    const int rb = rh*16 + lg*4;
    pv0 = Pt[(size_t)(rb + 0)*4096 + pcol];
    pv1 = Pt[(size_t)(rb + 1)*4096 + pcol];
    pv2 = Pt[(size_t)(rb + 2)*4096 + pcol];
    pv3 = Pt[(size_t)(rb + 3)*4096 + pcol];
  }
  SCK(6,10,0) SCK(7,8,0)
#undef SCK
#undef CCK

  // epilogue: inner sigmoid -> cross-gate exchange (sm aliases ring slot0: free)
  {
    int base = (uh*2 + (lr15 >> 3))*256 + (rh*16 + lg*4)*8 + (lr15 & 7);
    sm[base +  0] = sigm(acc[0] + bf2f(pv0));
    sm[base +  8] = sigm(acc[1] + bf2f(pv1));
    sm[base + 16] = sigm(acc[2] + bf2f(pv2));
    sm[base + 24] = sigm(acc[3] + bf2f(pv3));
  }
  __syncthreads();
  float2 h2;
  if (tid < 128) {
    int b0 = (tid >> 2)*8 + (tid & 3)*2;
    float f0 = sigm(sm[b0]),       f1 = sigm(sm[b0 + 1]);
    float i0 = sigm(sm[256 + b0]), i1 = sigm(sm[256 + b0 + 1]);
    float g0 = ftanh(sm[512 + b0]), g1 = ftanh(sm[512 + b0 + 1]);
    float o0 = sigm(sm[768 + b0]), o1 = sigm(sm[768 + b0 + 1]);
    float cn0 = f0*cx.x + i0*g0, cn1 = f1*cx.y + i1*g1;
    float h0 = o0*ftanh(cn0),    h1 = o1*ftanh(cn1);
    cx.x = cn0; cx.y = cn1; h2.x = h0; h2.y = h1;
    unsigned hp = (unsigned)f2bf(h0) | ((unsigned)f2bf(h1) << 16);
    __hip_atomic_store((unsigned*)&hxW[ci], hp,
                       __ATOMIC_RELAXED, __HIP_MEMORY_SCOPE_AGENT);
  }
  asm volatile("s_waitcnt vmcnt(0)" ::: "memory");   // hx at coherence point
  __syncthreads();
  if (tid == 0)
    __hip_atomic_store(fl + (size_t)cblk8*FLAG_STRIDE, t + 1,
                       __ATOMIC_RELAXED, __HIP_MEMORY_SCOPE_AGENT);
  if (tid < 128) *(float2*)&outt[ci] = h2;           // off publish path
}

__global__ __launch_bounds__(256, 1) void qlstm_scan(
    const ushort_t* __restrict__ P,      // [CHUNK*128][4096] bf16
    const ushort_t* __restrict__ W2,     // [4096][2048] bf16; U = cols [1024,2048)
    ushort_t* __restrict__ hxb,          // 3 rotating [128][1024] bf16
    float* __restrict__ cxg,             // [128][1024] f32 (chunk handoff)
    float* __restrict__ outc,            // d_out + c*CHUNK*BH
    int t0,
    unsigned* __restrict__ flags)        // [4 rblk][128 cblk8], 128B stride
{
  extern __shared__ __align__(16) ushort_t lds[];
  ushort_t* Ul  = lds;                   // [8 ck][32 Urows][128] swizzled, 64 KB
  ushort_t* ArA = lds + 32768;           // 4 slots x [32][128], 32 KB
  ushort_t* ArB = lds + 49152;           // 32 KB
  float* smA = (float*)ArA;              // alias slot 0 (epilogue only)
  float* smB = (float*)ArB;

  const int tid = threadIdx.x, wv = tid >> 6, ln = tid & 63;
  const int pr = blockIdx.x & 1, cblk8 = blockIdx.x >> 1;
  const int rA = 2*pr, rB = 2*pr + 1;
  const int uh = wv >> 1, lr15 = ln & 15;

  // ---- stage resident U once: 32 U-rows (4 gates x 8 cols) x K=1024
  for (int ck = 0; ck < 8; ++ck)
    #pragma unroll
    for (int rr = 0; rr < 2; ++rr) {
      int lrr = rr*16 + wv*4 + (ln >> 4);
      int grow = (lrr >> 3)*1024 + cblk8*8 + (lrr & 7);
      int gcol = ck*128 + (((ln & 15) ^ (lrr & 7)) << 3);
      lds16(W2 + (size_t)grow*2048 + 1024 + gcol, &Ul[ck*4096 + (rr*16 + wv*4)*128]);
    }

  // ---- epilogue slices (tid<128: 1 row x 2 adjacent cols per stream)
  size_t ciA = 0, ciB = 0;
  float2 cxA; cxA.x = 0.f; cxA.y = 0.f;
  float2 cxB; cxB.x = 0.f; cxB.y = 0.f;
  if (tid < 128) {
    int erow = tid >> 2, ec = (tid & 3)*2;
    ciA = (size_t)(rA*32 + erow)*1024 + cblk8*8 + ec;
    ciB = (size_t)(rB*32 + erow)*1024 + cblk8*8 + ec;
    cxA = *(const float2*)&cxg[ciA];
    cxB = *(const float2*)&cxg[ciB];
  }
  unsigned* flA = flags + (size_t)rA*128*FLAG_STRIDE;
  unsigned* flB = flags + (size_t)rB*128*FLAG_STRIDE;
  const int pcol = (uh*2 + (lr15 >> 3))*1024 + cblk8*8 + (lr15 & 7);

  asm volatile("s_waitcnt vmcnt(0)" ::: "memory");
  __syncthreads();

  for (int tl = 0; tl < CHUNK; ++tl) {
    const int t = t0 + tl;
    const ushort_t* hxR = hxb + (size_t)(t % 3)*BH;
    ushort_t*       hxW = hxb + (size_t)((t + 1) % 3)*BH;
    float* outt = outc + (size_t)tl*BH;
    stream_step(ArA, smA, Ul, hxR, hxW, rA*32, flA,
                P + (size_t)(tl*128 + rA*32)*4096, pcol,
                cxA, ciA, outt, (unsigned)t, wv, ln, tid, cblk8);
    stream_step(ArB, smB, Ul, hxR, hxW, rB*32, flB,
                P + (size_t)(tl*128 + rB*32)*4096, pcol,
                cxB, ciB, outt, (unsigned)t, wv, ln, tid, cblk8);
  }
  if (tid < 128) {
    *(float2*)&cxg[ciA] = cxA;
    *(float2*)&cxg[ciB] = cxB;
  }
}

extern "C" void kernel_launch(void* const* d_in, const int* in_sizes, int n_in,
                              void* d_out, int out_size, void* d_ws, size_t ws_size,
                              hipStream_t stream) {
  const float* x  = (const float*)d_in[0];   // (512,128,1024)
  const float* pW = (const float*)d_in[1];   // (4096,2048)
  const float* pb = (const float*)d_in[2];   // (4096)
  const float* qW = (const float*)d_in[3];   // (1024,1024)
  float* out = (float*)d_out;

  char* w = (char*)d_ws;
  auto carve = [&](size_t bytes) { char* p = w; w += (bytes + 255) & ~(size_t)255; return p; };
  ushort_t* qWbf = (ushort_t*)carve((size_t)HID*HID*2);
  ushort_t* pWt  = (ushort_t*)carve((size_t)2048*4096*2);
  ushort_t* W2   = (ushort_t*)carve((size_t)4096*2048*2);
  float*    b2   = (float*)   carve((size_t)4096*4);
  ushort_t* hxb  = (ushort_t*)carve((size_t)3*BH*2);
  float*    cxws = (float*)   carve((size_t)BH*4);
  unsigned* flags= (unsigned*)carve((size_t)4*128*FLAG_STRIDE*4);  // 64 KB
  ushort_t* xbf  = (ushort_t*)carve((size_t)CHUNK*BATCH*HID*2);
  ushort_t* Pc   = (ushort_t*)carve((size_t)CHUNK*BATCH*G4*2);

  (void)hipFuncSetAttribute((const void*)qlstm_scan,
                            hipFuncAttributeMaxDynamicSharedMemorySize, SCAN_LDS);
  (void)hipFuncSetAttribute((const void*)gemm256,
                            hipFuncAttributeMaxDynamicSharedMemorySize, GEMM256_LDS);

  // weight folding
  cast_f32_bf16<<<(HID*HID/4 + 255)/256, 256, 0, stream>>>(qW, qWbf, HID*HID/4);
  transpose_cast<<<dim3(64, 128), 256, 0, stream>>>(pW, pWt);
  bias_fold<<<4096, 64, 0, stream>>>(qW, pb, b2);
  gemm128<<<dim3(16, 32), 256, 0, stream>>>(qWbf, 1024, 1023u, pWt, 4096, ~1023u, nullptr, W2, 2048, 1024);

  hipMemsetAsync(hxb, 0, (size_t)BH*2, stream);        // h_{-1} = 0
  hipMemsetAsync(cxws, 0, (size_t)BH*4, stream);
  hipMemsetAsync(flags, 0, (size_t)4*128*FLAG_STRIDE*4, stream);

  for (int c = 0; c < SEQ/CHUNK; ++c) {
    cast_f32_bf16<<<(CHUNK*BATCH*HID/4 + 255)/256, 256, 0, stream>>>(
        x + (size_t)c*CHUNK*BATCH*HID, xbf, CHUNK*BATCH*HID/4);
    gemm256<<<dim3(G4/256, CHUNK*BATCH/256), 512, GEMM256_LDS, stream>>>(
        xbf, W2, b2, Pc);

    const ushort_t* Pa = Pc; const ushort_t* W2a = W2;
    ushort_t* hxa = hxb; float* cxa = cxws;
    float* outa = out + (size_t)c*CHUNK*BH;
    int t0 = c*CHUNK; unsigned* fla = flags;
    void* args[7] = { &Pa, &W2a, &hxa, &cxa, &outa, &t0, &fla };
    hipLaunchCooperativeKernel((const void*)qlstm_scan, dim3(NBLK), dim3(256),
                               args, SCAN_LDS, stream);
  }
  hipMemcpyAsync(out + (size_t)SEQ*BH,      out + (size_t)(SEQ-1)*BH, (size_t)BH*4,
                 hipMemcpyDeviceToDevice, stream);
  hipMemcpyAsync(out + (size_t)SEQ*BH + BH, cxws, (size_t)BH*4,
                 hipMemcpyDeviceToDevice, stream);
}

// Round 10
// 2981.086 us; speedup vs baseline: 3.9598x; 1.4786x over previous
//
#include <hip/hip_runtime.h>

typedef unsigned short ushort_t;
typedef __attribute__((ext_vector_type(4))) float f32x4;
typedef __attribute__((ext_vector_type(8))) __bf16 bf16x8;

#define SEQ   512
#define BATCH 128
#define HID   1024
#define G4    4096
#define CHUNK 64
#define BH    (BATCH*HID)
#define NBLK  256
#define FLAG_STRIDE 32
#define SCAN_LDS (131072 + 32768)
#define GEMM256_LDS 131072

__device__ __forceinline__ ushort_t f2bf(float f) {
  unsigned u = __float_as_uint(f);
  u += 0x7FFFu + ((u >> 16) & 1u);         // RNE
  return (ushort_t)(u >> 16);
}
__device__ __forceinline__ float bf2f(ushort_t h) {
  return __uint_as_float(((unsigned)h) << 16);
}
__device__ __forceinline__ float sigm(float x) { return 1.0f / (1.0f + __expf(-x)); }
__device__ __forceinline__ float ftanh(float x) {
  float xc = fminf(fmaxf(x, -15.f), 15.f);
  float t = __expf(2.f * xc);
  return (t - 1.f) / (t + 1.f);
}

__device__ __forceinline__ void lds16(const ushort_t* g, ushort_t* l) {
  __builtin_amdgcn_global_load_lds(
      (const __attribute__((address_space(1))) unsigned int*)g,
      (__attribute__((address_space(3))) unsigned int*)l, 16, 0, 0);
}
// coherent (SC0|SC1): read at coherence point -> no acquire fence needed
__device__ __forceinline__ void lds16c(const ushort_t* g, ushort_t* l) {
  __builtin_amdgcn_global_load_lds(
      (const __attribute__((address_space(1))) unsigned int*)g,
      (__attribute__((address_space(3))) unsigned int*)l, 16, 0, 0x11);
}

// ---------------- casts ----------------
__global__ void cast_f32_bf16(const float* __restrict__ in, ushort_t* __restrict__ out, int n4) {
  int i = blockIdx.x * blockDim.x + threadIdx.x;
  if (i < n4) {
    float4 v = ((const float4*)in)[i];
    union { ushort_t u[4]; uint2 v2; } o;
    o.u[0] = f2bf(v.x); o.u[1] = f2bf(v.y); o.u[2] = f2bf(v.z); o.u[3] = f2bf(v.w);
    ((uint2*)out)[i] = o.v2;
  }
}

__global__ __launch_bounds__(256) void transpose_cast(const float* __restrict__ pw, ushort_t* __restrict__ pwt) {
  __shared__ float tile[32][33];
  int bx = blockIdx.x, by = blockIdx.y;
  int tx = threadIdx.x & 31, ty = threadIdx.x >> 5;
  for (int i = 0; i < 32; i += 8)
    tile[ty + i][tx] = pw[(size_t)(by*32 + ty + i)*2048 + bx*32 + tx];
  __syncthreads();
  for (int i = 0; i < 32; i += 8) {
    int r = ty + i;
    pwt[(size_t)(bx*32 + r)*4096 + by*32 + tx] = f2bf(tile[tx][r]);
  }
}

__global__ void bias_fold(const float* __restrict__ qW, const float* __restrict__ pb, float* __restrict__ b2) {
  int r = blockIdx.x;
  int j = r & (HID-1), gb = r & ~(HID-1);
  float s = 0.f;
  for (int k = threadIdx.x; k < HID; k += 64)
    s += qW[(size_t)j*HID + k] * pb[gb + k];
  for (int off = 32; off; off >>= 1) s += __shfl_down(s, off, 64);
  if (threadIdx.x == 0) b2[r] = s;
}

// ---------------- 128x128 bf16 GEMM (m97 structure) — weight fold only
__global__ __launch_bounds__(256) void gemm128(
    const ushort_t* __restrict__ A, int lda, unsigned arow_mask,
    const ushort_t* __restrict__ B, int ldb, unsigned bko_mask,
    const float* __restrict__ bias, ushort_t* __restrict__ C, int ldc, int K)
{
  __shared__ __align__(16) ushort_t Al[128*64];
  __shared__ __align__(16) ushort_t Bl[128*64];
  const int tid = threadIdx.x, wv = tid >> 6, ln = tid & 63;
  const int bn = blockIdx.x, bm = blockIdx.y;
  const int bko = (int)(((unsigned)(bm << 7)) & bko_mask);
  const int m0 = (wv & 1) << 6, n0 = (wv >> 1) << 6;
  f32x4 acc[4][4] = {};
  for (int k0 = 0; k0 < K; k0 += 64) {
    for (int rr = 0; rr < 4; ++rr) {
      int r0 = (rr << 5) + (wv << 3);
      unsigned ga = ((unsigned)((bm << 7) + r0 + (ln >> 3))) & arow_mask;
      lds16(A + (size_t)ga*lda + k0 + ((ln & 7) << 3), &Al[r0 << 6]);
      unsigned gbr = (unsigned)((bn << 7) + r0 + (ln >> 3));
      lds16(B + (size_t)gbr*ldb + bko + k0 + ((ln & 7) << 3), &Bl[r0 << 6]);
    }
    __syncthreads();
    for (int kk = 0; kk < 64; kk += 32) {
      const int lrow = ln & 15, lk = kk + ((ln >> 4) << 3);
      bf16x8 af[4], bfr[4];
      for (int i = 0; i < 4; ++i) af[i]  = *(const bf16x8*)&Al[((m0 + (i << 4) + lrow) << 6) + lk];
      for (int j = 0; j < 4; ++j) bfr[j] = *(const bf16x8*)&Bl[((n0 + (j << 4) + lrow) << 6) + lk];
      for (int i = 0; i < 4; ++i)
        for (int j = 0; j < 4; ++j)
          acc[i][j] = __builtin_amdgcn_mfma_f32_16x16x32_bf16(af[i], bfr[j], acc[i][j], 0, 0, 0);
    }
    __syncthreads();
  }
  for (int i = 0; i < 4; ++i)
    for (int j = 0; j < 4; ++j) {
      int col = (bn << 7) + n0 + (j << 4) + (ln & 15);
      float bv = bias ? bias[col] : 0.f;
      for (int r = 0; r < 4; ++r) {
        int row = (bm << 7) + m0 + (i << 4) + ((ln >> 4) << 2) + r;
        C[(size_t)row*ldc + col] = f2bf(acc[i][j][r] + bv);
      }
    }
}

// ---------------- 256x256 8-phase bf16 GEMM: P = x @ V^T + b2 ----------------
// r6-verified body + T1 bijective XCD swizzle (512 WGs, 512%8==0).
__global__ __launch_bounds__(512) void gemm256(
    const ushort_t* __restrict__ A, const ushort_t* __restrict__ B,
    const float* __restrict__ bias, ushort_t* __restrict__ C)
{
  extern __shared__ __align__(16) ushort_t lds[];
  ushort_t* LA = lds;
  ushort_t* LB = lds + 32768;
  const int tid = threadIdx.x, wv8 = tid >> 6, ln = tid & 63;
  const int wm = wv8 >> 2, wn = wv8 & 3;
  // XCD swizzle: dispatch order is x-major; give each XCD a contiguous chunk.
  // Consecutive swz share bm (A-panel) -> XCD-L2 reuse of A and of B-tiles.
  const int flat = blockIdx.y * gridDim.x + blockIdx.x;     // 0..511
  const int swz  = ((flat & 7) << 6) | (flat >> 3);          // bijective
  const int bn = swz & 15, bm = swz >> 4;
  const int lr = ln & 15, lg = ln >> 4;

  f32x4 acc[8][4] = {};
  bf16x8 af[4][2], bfr[4][2];

  auto stA = [&](int db, int half, int kt) {
    ushort_t* d = LA + db*16384 + half*8192 + (wv8 << 9);
    const int ce = ((ln & 7) ^ (ln >> 3)) << 3;
    #pragma unroll
    for (int p = 0; p < 2; ++p) {
      int rr = half*128 + p*64 + (wv8 << 3) + (ln >> 3);
      lds16(A + (size_t)(bm*256 + rr)*1024 + kt*64 + ce, d + p*4096);
    }
  };
  auto stB = [&](int db, int half, int kt) {
    ushort_t* d = LB + db*16384 + half*8192 + (wv8 << 9);
    const int ce = ((ln & 7) ^ (ln >> 3)) << 3;
    #pragma unroll
    for (int p = 0; p < 2; ++p) {
      int rr = half*128 + p*64 + (wv8 << 3) + (ln >> 3);
      lds16(B + (size_t)(bn*256 + rr)*2048 + kt*64 + ce, d + p*4096);
    }
  };

#define RD_A(DB, MQ) { _Pragma("unroll") for (int i_ = 0; i_ < 4; ++i_) { \
    const int row_ = ((MQ)*4 + i_)*16 + lr; \
    const ushort_t* b_ = &LA[(DB)*16384 + wm*8192 + row_*64]; \
    af[i_][0] = *(const bf16x8*)&b_[ (lg << 3)       ^ ((lr & 7) << 3)]; \
    af[i_][1] = *(const bf16x8*)&b_[((lg << 3) | 32) ^ ((lr & 7) << 3)]; } }

#define RD_B(DB, NQ) { _Pragma("unroll") for (int j_ = 0; j_ < 2; ++j_) { \
    const int row_ = (wn & 1)*64 + ((NQ)*2 + j_)*16 + lr; \
    const ushort_t* b_ = &LB[(DB)*16384 + (wn >> 1)*8192 + row_*64]; \
    bfr[(NQ)*2 + j_][0] = *(const bf16x8*)&b_[ (lg << 3)       ^ ((lr & 7) << 3)]; \
    bfr[(NQ)*2 + j_][1] = *(const bf16x8*)&b_[((lg << 3) | 32) ^ ((lr & 7) << 3)]; } }

#define QUAD(MQ, NQ) \
  __builtin_amdgcn_s_setprio(1); \
  { _Pragma("unroll") for (int i_ = 0; i_ < 4; ++i_) \
      _Pragma("unroll") for (int j_ = 0; j_ < 2; ++j_) \
        _Pragma("unroll") for (int k_ = 0; k_ < 2; ++k_) \
          acc[(MQ)*4 + i_][(NQ)*2 + j_] = __builtin_amdgcn_mfma_f32_16x16x32_bf16( \
              af[i_][k_], bfr[(NQ)*2 + j_][k_], acc[(MQ)*4 + i_][(NQ)*2 + j_], 0, 0, 0); } \
  __builtin_amdgcn_s_setprio(0);

#define BAR() __builtin_amdgcn_s_barrier()
#define LGK0() do { asm volatile("s_waitcnt lgkmcnt(0)" ::: "memory"); \
                    __builtin_amdgcn_sched_barrier(0); } while (0)
#define VM4() do { asm volatile("s_waitcnt vmcnt(4)" ::: "memory"); \
                   __builtin_amdgcn_sched_barrier(0); } while (0)

  stA(0,0,0); stA(0,1,0); stB(0,0,0); stB(0,1,0); stB(1,0,1); stB(1,1,1);
  asm volatile("s_waitcnt vmcnt(4)" ::: "memory");
  BAR();

  for (int i = 0; i < 8; ++i) {
    const int k1 = 2*i + 1, k2 = 2*i + 2, k3 = 2*i + 3;
    RD_A(0,0); RD_B(0,0); stA(1,0,k1);            BAR(); LGK0(); QUAD(0,0); BAR();
    RD_B(0,1); stA(1,1,k1);                       BAR(); LGK0(); QUAD(0,1); BAR();
    RD_A(0,1); if (k2 < 16) stB(0,0,k2);          BAR(); LGK0(); QUAD(1,0); BAR();
    if (k2 < 16) stB(0,1,k2);                     BAR();         QUAD(1,1); VM4(); BAR();
    RD_A(1,0); RD_B(1,0); if (k2 < 16) stA(0,0,k2); BAR(); LGK0(); QUAD(0,0); BAR();
    RD_B(1,1); if (k2 < 16) stA(0,1,k2);          BAR(); LGK0(); QUAD(0,1); BAR();
    RD_A(1,1); if (k3 < 16) stB(1,0,k3);          BAR(); LGK0(); QUAD(1,0); BAR();
    if (k3 < 16) stB(1,1,k3);                     BAR();         QUAD(1,1); VM4(); BAR();
  }

  const int crow0 = bm*256 + wm*128;
  const int ccol0 = bn*256 + wn*64;
  #pragma unroll
  for (int m = 0; m < 8; ++m)
    #pragma unroll
    for (int n = 0; n < 4; ++n) {
      int col = ccol0 + n*16 + lr;
      float bv = bias[col];
      #pragma unroll
      for (int r = 0; r < 4; ++r) {
        int row = crow0 + m*16 + lg*4 + r;
        C[(size_t)row*4096 + col] = f2bf(acc[m][n][r] + bv);
      }
    }
#undef RD_A
#undef RD_B
#undef QUAD
#undef BAR
#undef LGK0
#undef VM4
}

// ---------------- persistent per-chunk scan kernel (r6-verified, unchanged) ----
__global__ __launch_bounds__(256, 1) void qlstm_scan(
    const ushort_t* __restrict__ P,
    const ushort_t* __restrict__ W2,
    ushort_t* __restrict__ hxb,
    float* __restrict__ cxg,
    float* __restrict__ outc,
    int t0,
    unsigned* __restrict__ flags)
{
  extern __shared__ __align__(16) ushort_t lds[];
  ushort_t* Ul = lds;
  ushort_t* Ar = lds + 65536;
  float*    sm = (float*)(lds + 65536);

  const int tid = threadIdx.x, wv = tid >> 6, ln = tid & 63;
  const int rblk = blockIdx.x & 3, cblk = blockIdx.x >> 2;
  unsigned* gflags = flags + (size_t)rblk*64*FLAG_STRIDE;

  for (int ck = 0; ck < 8; ++ck)
    for (int rr = 0; rr < 4; ++rr) {
      int lr = rr*16 + wv*4 + (ln >> 4);
      int grow = ((lr >> 4) << 10) + cblk*16 + (lr & 15);
      int gcol = ck*128 + (((ln & 15) ^ (lr & 7)) << 3);
      lds16(W2 + (size_t)grow*2048 + 1024 + gcol, &Ul[ck*8192 + (rr*16 + wv*4)*128]);
    }

  const int b_loc = tid >> 3;
  const int j0    = (tid & 7) << 1;
  const size_t ci = (size_t)(rblk*32 + b_loc)*1024 + cblk*16 + j0;
  float2 cxr = *(const float2*)&cxg[ci];

  auto stageA = [&](int slot, int k0, const ushort_t* hxR) {
    #pragma unroll
    for (int rr = 0; rr < 2; ++rr) {
      int row = rr*16 + wv*4 + (ln >> 4);
      int gcol = ((ln & 15) ^ (row & 7)) << 3;
      lds16c(hxR + (size_t)(rblk*32 + row)*1024 + k0 + gcol,
             &Ar[slot*4096 + (rr*16 + wv*4)*128]);
    }
  };
  auto load_pv = [&](int tl, float* pv) {
    #pragma unroll
    for (int i = 0; i < 2; ++i)
      #pragma unroll
      for (int r = 0; r < 4; ++r) {
        int bl = i*16 + ((ln >> 4) << 2) + r;
        pv[i*4+r] = bf2f(P[(size_t)(tl*128 + rblk*32 + bl)*4096 + (wv << 10) + cblk*16 + (ln & 15)]);
      }
  };

  float pv[8];
  load_pv(0, pv);

  for (int tl = 0; tl < CHUNK; ++tl) {
    const int t = t0 + tl;
    const ushort_t* hxR = hxb + (size_t)(t % 3)*BH;
    ushort_t*       hxW = hxb + (size_t)((t + 1) % 3)*BH;

    f32x4 acc0 = {}, acc1 = {};
    stageA(0, 0, hxR);
    stageA(1, 128, hxR);
    stageA(2, 256, hxR);

    #define COMPUTE_CK(CK)                                                         \
      {                                                                            \
        const int aslot = (CK) & 3;                                                \
        _Pragma("unroll")                                                          \
        for (int k4 = 0; k4 < 4; ++k4) {                                           \
          int s = k4*4 + (ln >> 4);                                                \
          int ar0 = ln & 15, ar1 = 16 + (ln & 15);                                 \
          int brow = wv*16 + (ln & 15);                                            \
          bf16x8 a0 = *(const bf16x8*)&Ar[aslot*4096 + ar0*128 + ((s ^ (ar0 & 7)) << 3)]; \
          bf16x8 a1 = *(const bf16x8*)&Ar[aslot*4096 + ar1*128 + ((s ^ (ar1 & 7)) << 3)]; \
          bf16x8 bb = *(const bf16x8*)&Ul[(CK)*8192 + brow*128 + ((s ^ (brow & 7)) << 3)]; \
          acc0 = __builtin_amdgcn_mfma_f32_16x16x32_bf16(a0, bb, acc0, 0, 0, 0);   \
          acc1 = __builtin_amdgcn_mfma_f32_16x16x32_bf16(a1, bb, acc1, 0, 0, 0);   \
        }                                                                          \
      }
    #define STEP_CK(CK, WN, DOSTAGE)                                               \
      asm volatile("s_waitcnt vmcnt(" #WN ")" ::: "memory");                       \
      __builtin_amdgcn_s_barrier();                                                \
      if (DOSTAGE) stageA(((CK)+3) & 3, ((CK)+3)*128, hxR);                        \
      COMPUTE_CK(CK)

    STEP_CK(0, 4, 1) STEP_CK(1, 4, 1) STEP_CK(2, 4, 1)
    STEP_CK(3, 4, 1) STEP_CK(4, 4, 1)
    STEP_CK(5, 4, 0) STEP_CK(6, 2, 0) STEP_CK(7, 0, 0)
    #undef STEP_CK
    #undef COMPUTE_CK

    #pragma unroll
    for (int i = 0; i < 2; ++i)
      #pragma unroll
      for (int r = 0; r < 4; ++r) {
        int bl = i*16 + ((ln >> 4) << 2) + r;
        float v = (i ? acc1[r] : acc0[r]) + pv[i*4+r];
        sm[wv*512 + bl*16 + (ln & 15)] = sigm(v);
      }
    __syncthreads();
    float2 h2;
    {
      const float2* sm2 = (const float2*)sm;
      int e = b_loc*8 + (j0 >> 1);
      float2 sF = sm2[0*256 + e], sI = sm2[1*256 + e];
      float2 sG = sm2[2*256 + e], sO = sm2[3*256 + e];
      float f0 = sigm(sF.x), i0 = sigm(sI.x), g0 = ftanh(sG.x), o0 = sigm(sO.x);
      float f1 = sigm(sF.y), i1 = sigm(sI.y), g1 = ftanh(sG.y), o1 = sigm(sO.y);
      float cn0 = f0*cxr.x + i0*g0, cn1 = f1*cxr.y + i1*g1;
      float h0 = o0*ftanh(cn0),     h1 = o1*ftanh(cn1);
      cxr.x = cn0; cxr.y = cn1;
      h2.x = h0; h2.y = h1;
      unsigned hp = (unsigned)f2bf(h0) | ((unsigned)f2bf(h1) << 16);
      __hip_atomic_store((unsigned*)&hxW[ci], hp,
                         __ATOMIC_RELAXED, __HIP_MEMORY_SCOPE_AGENT);
    }

    if (tl != CHUNK - 1) {
      const unsigned gen = (unsigned)(t + 1);
      asm volatile("s_waitcnt vmcnt(0)" ::: "memory");
      __syncthreads();
      if (tid == 0)
        __hip_atomic_store(gflags + (size_t)cblk*FLAG_STRIDE, gen,
                           __ATOMIC_RELAXED, __HIP_MEMORY_SCOPE_AGENT);
      *(float2*)&outc[(size_t)tl*BH + ci] = h2;
      float pvn[8];
      load_pv(tl + 1, pvn);
      if (tid < 64) {
        int it = 0;
        for (;;) {
          unsigned a = __hip_atomic_load(gflags + (size_t)tid*FLAG_STRIDE,
                                         __ATOMIC_RELAXED, __HIP_MEMORY_SCOPE_AGENT);
          if (__all(a >= gen)) break;
          if ((++it & 255) == 0) __builtin_amdgcn_fence(__ATOMIC_ACQUIRE, "agent");
          __builtin_amdgcn_s_sleep(1);
        }
      }
      __syncthreads();
      #pragma unroll
      for (int q = 0; q < 8; ++q) pv[q] = pvn[q];
    } else {
      *(float2*)&outc[(size_t)tl*BH + ci] = h2;
    }
  }
  *(float2*)&cxg[ci] = cxr;
}

extern "C" void kernel_launch(void* const* d_in, const int* in_sizes, int n_in,
                              void* d_out, int out_size, void* d_ws, size_t ws_size,
                              hipStream_t stream) {
  const float* x  = (const float*)d_in[0];   // (512,128,1024)
  const float* pW = (const float*)d_in[1];   // (4096,2048)
  const float* pb = (const float*)d_in[2];   // (4096)
  const float* qW = (const float*)d_in[3];   // (1024,1024)
  float* out = (float*)d_out;

  char* w = (char*)d_ws;
  auto carve = [&](size_t bytes) { char* p = w; w += (bytes + 255) & ~(size_t)255; return p; };
  ushort_t* qWbf = (ushort_t*)carve((size_t)HID*HID*2);
  ushort_t* pWt  = (ushort_t*)carve((size_t)2048*4096*2);
  ushort_t* W2   = (ushort_t*)carve((size_t)4096*2048*2);
  float*    b2   = (float*)   carve((size_t)4096*4);
  ushort_t* hxb  = (ushort_t*)carve((size_t)3*BH*2);
  float*    cxws = (float*)   carve((size_t)BH*4);
  unsigned* flags= (unsigned*)carve((size_t)NBLK*FLAG_STRIDE*4);
  ushort_t* xbf  = (ushort_t*)carve((size_t)CHUNK*BATCH*HID*2);
  ushort_t* Pc   = (ushort_t*)carve((size_t)CHUNK*BATCH*G4*2);

  (void)hipFuncSetAttribute((const void*)qlstm_scan,
                            hipFuncAttributeMaxDynamicSharedMemorySize, SCAN_LDS);
  (void)hipFuncSetAttribute((const void*)gemm256,
                            hipFuncAttributeMaxDynamicSharedMemorySize, GEMM256_LDS);

  // weight folding
  cast_f32_bf16<<<(HID*HID/4 + 255)/256, 256, 0, stream>>>(qW, qWbf, HID*HID/4);
  transpose_cast<<<dim3(64, 128), 256, 0, stream>>>(pW, pWt);
  bias_fold<<<4096, 64, 0, stream>>>(qW, pb, b2);
  gemm128<<<dim3(16, 32), 256, 0, stream>>>(qWbf, 1024, 1023u, pWt, 4096, ~1023u, nullptr, W2, 2048, 1024);

  hipMemsetAsync(hxb, 0, (size_t)BH*2, stream);        // h_{-1} = 0
  hipMemsetAsync(cxws, 0, (size_t)BH*4, stream);
  hipMemsetAsync(flags, 0, (size_t)NBLK*FLAG_STRIDE*4, stream);

  for (int c = 0; c < SEQ/CHUNK; ++c) {
    cast_f32_bf16<<<(CHUNK*BATCH*HID/4 + 255)/256, 256, 0, stream>>>(
        x + (size_t)c*CHUNK*BATCH*HID, xbf, CHUNK*BATCH*HID/4);
    gemm256<<<dim3(G4/256, CHUNK*BATCH/256), 512, GEMM256_LDS, stream>>>(
        xbf, W2, b2, Pc);

    const ushort_t* Pa = Pc; const ushort_t* W2a = W2;
    ushort_t* hxa = hxb; float* cxa = cxws;
    float* outa = out + (size_t)c*CHUNK*BH;
    int t0 = c*CHUNK; unsigned* fla = flags;
    void* args[7] = { &Pa, &W2a, &hxa, &cxa, &outa, &t0, &fla };
    hipLaunchCooperativeKernel((const void*)qlstm_scan, dim3(NBLK), dim3(256),
                               args, SCAN_LDS, stream);
  }
  hipMemcpyAsync(out + (size_t)SEQ*BH,      out + (size_t)(SEQ-1)*BH, (size_t)BH*4,
                 hipMemcpyDeviceToDevice, stream);
  hipMemcpyAsync(out + (size_t)SEQ*BH + BH, cxws, (size_t)BH*4,
                 hipMemcpyDeviceToDevice, stream);
}